// Round 9
// baseline (55.481 us; speedup 1.0000x reference)
//
#include <hip/hip_runtime.h>
#include <math.h>

#define HH 128   // hidden size
#define SS 1000  // sequence length
#define NT 1024  // threads per block (16 waves)
#define NW (NT / 64)

#define C1 2.8853900817779268f  // 2*log2(e)
#define C2 1.4426950408889634f  // log2(e)

typedef float v2f __attribute__((ext_vector_type(2)));

// DPP add helpers. row_shr:N sums within 16-lane rows; row_bcast15 (0x142)
// pushes each row's lane15 into the next row (completes 32-lane group sums
// at lanes 31 and 63). Verified in R8 (absmax 0).
template <int CTRL>
__device__ __forceinline__ float dpp_add(float x) {
    int s = __builtin_amdgcn_update_dpp(0, __builtin_bit_cast(int, x),
                                        CTRL, 0xF, 0xF, true);
    return x + __builtin_bit_cast(float, s);
}

__global__ __launch_bounds__(NT) void sc_fused(
    const float* __restrict__ stat, const float* __restrict__ dyn,
    const float* __restrict__ enc_s_w, const float* __restrict__ enc_s_b,
    const float* __restrict__ enc_d_w, const float* __restrict__ enc_d_b,
    const float* __restrict__ v, const float* __restrict__ W,
    const float* __restrict__ dense_w, const float* __restrict__ dense_b,
    const float* __restrict__ lin_w, const float* __restrict__ lin_b,
    float* __restrict__ out) {
    const int b    = blockIdx.x;
    const int t    = threadIdx.x;
    const int wave = t >> 6;
    const int lane = t & 63;
    const int g    = t & 31;   // h-slice: h = 4g .. 4g+3
    const int sg   = t >> 5;   // s-group 0..31; s = pass*32 + sg

    __shared__ __align__(16) float4 xs[NT];    // {x0,x1,yv,0} per s (16 KB)
    __shared__ __align__(16) float kc[8][HH];  // folded constants (4 KB)
    __shared__ float logit_sh[NT];             // per-s logits (4 KB)
    __shared__ float4 red4[NW];
    __shared__ float hy_sh[HH];
    __shared__ float svc2_sh;

    // ---- phase 0: stage per-s inputs (coalesced); keep own x in regs ----
    float x0r = 0.f, x1r = 0.f;
    {
        float yv = 0.f;
        if (t < SS) {
            const float* sb = stat + (size_t)b * 2 * SS;
            x0r = sb[t];
            x1r = sb[SS + t];
            yv  = dyn[(size_t)b * 2 * SS + SS + t];
        }
        xs[t] = make_float4(x0r, x1r, yv, 0.f);
    }

    // ---- phase 1: constant folding, split-k over 8 lanes, DPP reduce ----
    {
        const int fh = t >> 3;   // h = 0..127
        const int fq = t & 7;    // k-eighth
        const float4* W1 = (const float4*)(W + fh * (3 * HH));
        const float4* W2 = (const float4*)(W + fh * (3 * HH) + HH);
        const float4* W3 = (const float4*)(W + fh * (3 * HH) + 2 * HH);
        const float4* ES = (const float4*)enc_s_w;
        const float4* ED = (const float4*)enc_d_w;
        const float4* SB = (const float4*)enc_s_b;
        const float4* DB = (const float4*)enc_d_b;
        float a0 = 0.f, a1 = 0.f, ad = 0.f, cc = 0.f, w30 = 0.f, w31 = 0.f, w3b = 0.f;
        #pragma unroll
        for (int j = 0; j < 4; ++j) {
            const int k4 = fq * 4 + j;
            float4 w1 = W1[k4], w2 = W2[k4], w3 = W3[k4];
            float4 e01 = ES[2 * k4], e23 = ES[2 * k4 + 1];
            float4 d01 = ED[2 * k4], d23 = ED[2 * k4 + 1];
            float4 sb = SB[k4], db = DB[k4];
            a0 = fmaf(w1.x, e01.x, a0); a0 = fmaf(w1.y, e01.z, a0);
            a0 = fmaf(w1.z, e23.x, a0); a0 = fmaf(w1.w, e23.z, a0);
            a1 = fmaf(w1.x, e01.y, a1); a1 = fmaf(w1.y, e01.w, a1);
            a1 = fmaf(w1.z, e23.y, a1); a1 = fmaf(w1.w, e23.w, a1);
            ad = fmaf(w2.x, d01.x + d01.y, ad); ad = fmaf(w2.y, d01.z + d01.w, ad);
            ad = fmaf(w2.z, d23.x + d23.y, ad); ad = fmaf(w2.w, d23.z + d23.w, ad);
            cc = fmaf(w1.x, sb.x, cc); cc = fmaf(w1.y, sb.y, cc);
            cc = fmaf(w1.z, sb.z, cc); cc = fmaf(w1.w, sb.w, cc);
            cc = fmaf(w2.x, db.x, cc); cc = fmaf(w2.y, db.y, cc);
            cc = fmaf(w2.z, db.z, cc); cc = fmaf(w2.w, db.w, cc);
            w30 = fmaf(w3.x, e01.x, w30); w30 = fmaf(w3.y, e01.z, w30);
            w30 = fmaf(w3.z, e23.x, w30); w30 = fmaf(w3.w, e23.z, w30);
            w31 = fmaf(w3.x, e01.y, w31); w31 = fmaf(w3.y, e01.w, w31);
            w31 = fmaf(w3.z, e23.y, w31); w31 = fmaf(w3.w, e23.w, w31);
            w3b = fmaf(w3.x, sb.x, w3b); w3b = fmaf(w3.y, sb.y, w3b);
            w3b = fmaf(w3.z, sb.z, w3b); w3b = fmaf(w3.w, sb.w, w3b);
        }
        a0  = dpp_add<0x111>(a0);  a0  = dpp_add<0x112>(a0);  a0  = dpp_add<0x114>(a0);
        a1  = dpp_add<0x111>(a1);  a1  = dpp_add<0x112>(a1);  a1  = dpp_add<0x114>(a1);
        ad  = dpp_add<0x111>(ad);  ad  = dpp_add<0x112>(ad);  ad  = dpp_add<0x114>(ad);
        cc  = dpp_add<0x111>(cc);  cc  = dpp_add<0x112>(cc);  cc  = dpp_add<0x114>(cc);
        w30 = dpp_add<0x111>(w30); w30 = dpp_add<0x112>(w30); w30 = dpp_add<0x114>(w30);
        w31 = dpp_add<0x111>(w31); w31 = dpp_add<0x112>(w31); w31 = dpp_add<0x114>(w31);
        w3b = dpp_add<0x111>(w3b); w3b = dpp_add<0x112>(w3b); w3b = dpp_add<0x114>(w3b);
        if (fq == 7) {
            kc[0][fh] = a0 * C1;
            kc[1][fh] = a1 * C1;
            kc[2][fh] = ad * C1;
            kc[4][fh] = cc * C1;
            kc[5][fh] = (cc + w3b) * C1;
            kc[6][fh] = w30 * C1;
            kc[7][fh] = w31 * C1;
        }
        if (t < HH) kc[3][t] = v[t];
        if (t < 32) {  // sum(v)
            float4 x = ((const float4*)v)[t];
            float s = (x.x + x.y) + (x.z + x.w);
            #pragma unroll
            for (int off = 1; off < 32; off <<= 1) s += __shfl_xor(s, off);
            if (t == 0) svc2_sh = s * C2;
        }
    }
    __syncthreads();

    // ---- phase 2: 16 resident constant floats + pair sums ----
    const int h4 = g * 4;
    float4 u;
    u = *(const float4*)&kc[0][h4]; const v2f a0_0 = {u.x, u.y}, a0_1 = {u.z, u.w};
    u = *(const float4*)&kc[1][h4]; const v2f a1_0 = {u.x, u.y}, a1_1 = {u.z, u.w};
    u = *(const float4*)&kc[2][h4]; const v2f ad_0 = {u.x, u.y}, ad_1 = {u.z, u.w};
    u = *(const float4*)&kc[3][h4]; const v2f vv_0 = {u.x, u.y}, vv_1 = {u.z, u.w};
    const float c01 = vv_0.x + vv_0.y;   // v0+v1
    const float c23 = vv_1.x + vv_1.y;   // v2+v3
    const float svc2 = svc2_sh;
    const v2f clampv = {28.f, 28.f};
    const bool owner = (g == 31);

    float X0 = 0.f, X1 = 0.f;

    for (int iter = 0; iter < 3; ++iter) {
        v2f cg_0, cg_1;
        if (iter == 0) {
            u = *(const float4*)&kc[4][h4];
            cg_0 = (v2f){u.x, u.y};
            cg_1 = (v2f){u.z, u.w};
        } else {
            float4 ub = *(const float4*)&kc[5][h4];
            float4 u0 = *(const float4*)&kc[6][h4];
            float4 u1 = *(const float4*)&kc[7][h4];
            v2f X0v = {X0, X0}, X1v = {X1, X1};
            cg_0 = __builtin_elementwise_fma(
                (v2f){u0.x, u0.y}, X0v,
                __builtin_elementwise_fma((v2f){u1.x, u1.y}, X1v, (v2f){ub.x, ub.y}));
            cg_1 = __builtin_elementwise_fma(
                (v2f){u0.z, u0.w}, X0v,
                __builtin_elementwise_fma((v2f){u1.z, u1.w}, X1v, (v2f){ub.z, ub.w}));
        }

        // ---- phase A: logits only; owner lane stores to LDS ----
        #pragma unroll 4
        for (int pass = 0; pass < 32; ++pass) {
            const int s = pass * 32 + sg;
            float4 x = xs[s];
            v2f vx0 = {x.x, x.x}, vx1 = {x.y, x.y}, vyv = {x.z, x.z};
            v2f z0 = __builtin_elementwise_fma(
                a0_0, vx0, __builtin_elementwise_fma(
                    a1_0, vx1, __builtin_elementwise_fma(ad_0, vyv, cg_0)));
            v2f z1 = __builtin_elementwise_fma(
                a0_1, vx0, __builtin_elementwise_fma(
                    a1_1, vx1, __builtin_elementwise_fma(ad_1, vyv, cg_1)));
            z0 = __builtin_elementwise_min(z0, clampv);  // e <= 2^28: products finite
            z1 = __builtin_elementwise_min(z1, clampv);
            float e0 = __builtin_amdgcn_exp2f(z0.x);
            float e1 = __builtin_amdgcn_exp2f(z0.y);
            float e2 = __builtin_amdgcn_exp2f(z1.x);
            float e3 = __builtin_amdgcn_exp2f(z1.y);
            // sum of 4 sigmoids with ONE rcp:
            //   v0/(1+e0)+v1/(1+e1) = (c01 + v0*e1 + v1*e0) / ((1+e0)(1+e1))
            float t1  = 1.f + e1, t3 = 1.f + e3;
            float d01 = fmaf(e0, t1, t1);
            float d23 = fmaf(e2, t3, t3);
            float n01 = fmaf(vv_0.x, e1, fmaf(vv_0.y, e0, c01));
            float n23 = fmaf(vv_1.x, e3, fmaf(vv_1.y, e2, c23));
            float num = fmaf(n01, d23, n23 * d01);
            float den = d01 * d23;
            float acc = num * __builtin_amdgcn_rcpf(den);
            // 32-lane group sum -> lanes 31 and 63
            acc = dpp_add<0x111>(acc);
            acc = dpp_add<0x112>(acc);
            acc = dpp_add<0x114>(acc);
            acc = dpp_add<0x118>(acc);
            acc = dpp_add<0x142>(acc);
            if (owner) logit_sh[s] = acc;
        }
        __syncthreads();  // logits visible

        // ---- phase B: one exp2 per s; block-reduce S, S*x0, S*x1 ----
        float pp = 0.f;
        if (t < SS) pp = __builtin_amdgcn_exp2f(fmaf(-C1, logit_sh[t], svc2));
        float S = pp, Sx0 = pp * x0r, Sx1 = pp * x1r;
        #pragma unroll
        for (int off = 32; off > 0; off >>= 1) {
            S   += __shfl_xor(S, off);
            Sx0 += __shfl_xor(Sx0, off);
            Sx1 += __shfl_xor(Sx1, off);
        }
        if (lane == 0) red4[wave] = make_float4(S, Sx0, Sx1, 0.f);
        __syncthreads();  // red4 visible
        float4 w4 = red4[lane & 15];
        #pragma unroll
        for (int off = 1; off < 16; off <<= 1) {
            w4.x += __shfl_xor(w4.x, off);
            w4.y += __shfl_xor(w4.y, off);
            w4.z += __shfl_xor(w4.z, off);
        }
        float inv = __builtin_amdgcn_rcpf(w4.x);
        X0 = w4.y * inv;  // uniform across block
        X1 = w4.z * inv;
    }

    // hy[h] = enc_s_w[h,0]*X0 + enc_s_w[h,1]*X1 + enc_s_b[h]
    if (t < HH)
        hy_sh[t] = fmaf(enc_s_w[2 * t], X0, fmaf(enc_s_w[2 * t + 1], X1, enc_s_b[t]));
    __syncthreads();

    // out[b] = lin_w @ relu(dense_w @ hy + dense_b) + lin_b
    float o = 0.f;
    if (t < HH) {
        const float4* dw4 = (const float4*)(dense_w + t * HH);
        const float4* hy4 = (const float4*)hy_sh;
        float r = dense_b[t];
        #pragma unroll 4
        for (int k = 0; k < HH / 4; ++k) {
            float4 d4 = dw4[k], h4v = hy4[k];
            r = fmaf(d4.x, h4v.x, fmaf(d4.y, h4v.y, fmaf(d4.z, h4v.z, fmaf(d4.w, h4v.w, r))));
        }
        o = lin_w[t] * fmaxf(r, 0.f);
    }
    #pragma unroll
    for (int off = 32; off > 0; off >>= 1) o += __shfl_xor(o, off);
    if (lane == 0) red4[wave].x = o;
    __syncthreads();
    if (t == 0) {
        float s = 0.f;
        for (int i = 0; i < NW; ++i) s += red4[i].x;
        out[b] = s + lin_b[0];
    }
}

extern "C" void kernel_launch(void* const* d_in, const int* in_sizes, int n_in,
                              void* d_out, int out_size, void* d_ws, size_t ws_size,
                              hipStream_t stream) {
    const float* stat    = (const float*)d_in[0];
    const float* dyn     = (const float*)d_in[1];
    const float* enc_s_w = (const float*)d_in[2];
    const float* enc_s_b = (const float*)d_in[3];
    const float* enc_d_w = (const float*)d_in[4];
    const float* enc_d_b = (const float*)d_in[5];
    const float* v       = (const float*)d_in[6];
    const float* W       = (const float*)d_in[7];
    const float* dense_w = (const float*)d_in[8];
    const float* dense_b = (const float*)d_in[9];
    const float* lin_w   = (const float*)d_in[10];
    const float* lin_b   = (const float*)d_in[11];
    float* out = (float*)d_out;

    const int B = in_sizes[0] / (2 * SS);

    hipLaunchKernelGGL(sc_fused, dim3(B), dim3(NT), 0, stream,
                       stat, dyn, enc_s_w, enc_s_b, enc_d_w, enc_d_b, v, W,
                       dense_w, dense_b, lin_w, lin_b, out);
}

// Round 10
// 54.191 us; speedup vs baseline: 1.0238x; 1.0238x over previous
//
#include <hip/hip_runtime.h>
#include <math.h>

#define HH  128   // hidden size
#define SS  1000  // sequence length
#define NSH 500   // s per half-batch block
#define NT  1024
#define C1 2.8853900817779268f  // 2*log2(e)
#define C2 1.4426950408889634f  // log2(e)

typedef float v2f __attribute__((ext_vector_type(2)));

// DPP adds: row_shr within 16-lane rows; row_bcast15 completes 32-lane sums
// at lanes 31/63. Chain verified bit-exact in R8/R9.
template <int CTRL>
__device__ __forceinline__ float dpp_add(float x) {
    int s = __builtin_amdgcn_update_dpp(0, __builtin_bit_cast(int, x),
                                        CTRL, 0xF, 0xF, true);
    return x + __builtin_bit_cast(float, s);
}

// ws float layout:
//   [0..1024)  kc rows 0..7  (row*128 + h):
//     0:a0*C1 1:a1*C1 2:ad*C1 3:v 4:cc*C1 5:(cc+w3b)*C1 6:w30*C1 7:w31*C1
//   [1024]     svc2 = sum(v)*log2(e)
//   [1088 + ((iter*B + b)*2 + half)*4]  partial float4 {S, Sx0, Sx1, 0}
#define WS_PART 1088

// ---- fold kernel: grid 4 x 1024. Block bx covers h in [bx*32, bx*32+32). ----
__global__ __launch_bounds__(NT) void sc_fold(
    const float* __restrict__ enc_s_w, const float* __restrict__ enc_s_b,
    const float* __restrict__ enc_d_w, const float* __restrict__ enc_d_b,
    const float* __restrict__ v, const float* __restrict__ W,
    float* __restrict__ ws) {
    const int t  = threadIdx.x;
    const int fh = blockIdx.x * 32 + (t >> 5);  // h
    const int fq = t & 31;                      // k-quad index (float4 #fq)
    const float4* W1 = (const float4*)(W + fh * (3 * HH));
    const float4* W2 = (const float4*)(W + fh * (3 * HH) + HH);
    const float4* W3 = (const float4*)(W + fh * (3 * HH) + 2 * HH);
    const float4* ES = (const float4*)enc_s_w;
    const float4* ED = (const float4*)enc_d_w;
    const float4* SB = (const float4*)enc_s_b;
    const float4* DB = (const float4*)enc_d_b;
    const int k4 = fq;
    float4 w1 = W1[k4], w2 = W2[k4], w3 = W3[k4];
    float4 e01 = ES[2 * k4], e23 = ES[2 * k4 + 1];
    float4 d01 = ED[2 * k4], d23 = ED[2 * k4 + 1];
    float4 sb = SB[k4], db = DB[k4];
    float a0 = 0.f, a1 = 0.f, ad = 0.f, cc = 0.f, w30 = 0.f, w31 = 0.f, w3b = 0.f;
    a0 = fmaf(w1.x, e01.x, a0); a0 = fmaf(w1.y, e01.z, a0);
    a0 = fmaf(w1.z, e23.x, a0); a0 = fmaf(w1.w, e23.z, a0);
    a1 = fmaf(w1.x, e01.y, a1); a1 = fmaf(w1.y, e01.w, a1);
    a1 = fmaf(w1.z, e23.y, a1); a1 = fmaf(w1.w, e23.w, a1);
    ad = fmaf(w2.x, d01.x + d01.y, ad); ad = fmaf(w2.y, d01.z + d01.w, ad);
    ad = fmaf(w2.z, d23.x + d23.y, ad); ad = fmaf(w2.w, d23.z + d23.w, ad);
    cc = fmaf(w1.x, sb.x, cc); cc = fmaf(w1.y, sb.y, cc);
    cc = fmaf(w1.z, sb.z, cc); cc = fmaf(w1.w, sb.w, cc);
    cc = fmaf(w2.x, db.x, cc); cc = fmaf(w2.y, db.y, cc);
    cc = fmaf(w2.z, db.z, cc); cc = fmaf(w2.w, db.w, cc);
    w30 = fmaf(w3.x, e01.x, w30); w30 = fmaf(w3.y, e01.z, w30);
    w30 = fmaf(w3.z, e23.x, w30); w30 = fmaf(w3.w, e23.z, w30);
    w31 = fmaf(w3.x, e01.y, w31); w31 = fmaf(w3.y, e01.w, w31);
    w31 = fmaf(w3.z, e23.y, w31); w31 = fmaf(w3.w, e23.w, w31);
    w3b = fmaf(w3.x, sb.x, w3b); w3b = fmaf(w3.y, sb.y, w3b);
    w3b = fmaf(w3.z, sb.z, w3b); w3b = fmaf(w3.w, sb.w, w3b);
    // 32-lane sum -> lanes 31/63 of each wave (fq groups are 32-aligned)
    a0  = dpp_add<0x111>(a0);  a0  = dpp_add<0x112>(a0);  a0  = dpp_add<0x114>(a0);
    a0  = dpp_add<0x118>(a0);  a0  = dpp_add<0x142>(a0);
    a1  = dpp_add<0x111>(a1);  a1  = dpp_add<0x112>(a1);  a1  = dpp_add<0x114>(a1);
    a1  = dpp_add<0x118>(a1);  a1  = dpp_add<0x142>(a1);
    ad  = dpp_add<0x111>(ad);  ad  = dpp_add<0x112>(ad);  ad  = dpp_add<0x114>(ad);
    ad  = dpp_add<0x118>(ad);  ad  = dpp_add<0x142>(ad);
    cc  = dpp_add<0x111>(cc);  cc  = dpp_add<0x112>(cc);  cc  = dpp_add<0x114>(cc);
    cc  = dpp_add<0x118>(cc);  cc  = dpp_add<0x142>(cc);
    w30 = dpp_add<0x111>(w30); w30 = dpp_add<0x112>(w30); w30 = dpp_add<0x114>(w30);
    w30 = dpp_add<0x118>(w30); w30 = dpp_add<0x142>(w30);
    w31 = dpp_add<0x111>(w31); w31 = dpp_add<0x112>(w31); w31 = dpp_add<0x114>(w31);
    w31 = dpp_add<0x118>(w31); w31 = dpp_add<0x142>(w31);
    w3b = dpp_add<0x111>(w3b); w3b = dpp_add<0x112>(w3b); w3b = dpp_add<0x114>(w3b);
    w3b = dpp_add<0x118>(w3b); w3b = dpp_add<0x142>(w3b);
    if (fq == 31) {
        ws[0 * HH + fh] = a0 * C1;
        ws[1 * HH + fh] = a1 * C1;
        ws[2 * HH + fh] = ad * C1;
        ws[4 * HH + fh] = cc * C1;
        ws[5 * HH + fh] = (cc + w3b) * C1;
        ws[6 * HH + fh] = w30 * C1;
        ws[7 * HH + fh] = w31 * C1;
    }
    if (blockIdx.x == 0) {
        if (t < HH) ws[3 * HH + t] = v[t];
        if (t < 32) {
            float4 x = ((const float4*)v)[t];
            float s = (x.x + x.y) + (x.z + x.w);
            #pragma unroll
            for (int off = 1; off < 32; off <<= 1) s += __shfl_xor(s, off);
            if (t == 0) ws[8 * HH] = s * C2;
        }
    }
}

// ---- iter kernel: grid 2B x 1024. Block = (batch, half). 16 passes. ----
__global__ __launch_bounds__(NT) void sc_iter(
    const float* __restrict__ stat, const float* __restrict__ dyn,
    float* __restrict__ ws, int B, int iter) {
    const int bid  = blockIdx.x;
    const int b    = bid >> 1;
    const int half = bid & 1;
    const int t    = threadIdx.x;
    const int lane = t & 63;
    const int g    = t & 31;   // h-slice: h = 4g .. 4g+3
    const int sg   = t >> 5;   // s-slot 0..31; s_local = pass*32 + sg

    __shared__ __align__(16) float4 xs[512];
    __shared__ float4 red4[NT / 64];

    // stage this half's inputs (s_local >= NSH slots stay zero)
    if (t < 512) {
        float x0 = 0.f, x1 = 0.f, yv = 0.f;
        if (t < NSH) {
            const int s = half * NSH + t;
            const float* sbp = stat + (size_t)b * 2 * SS;
            x0 = sbp[s];
            x1 = sbp[SS + s];
            yv = dyn[(size_t)b * 2 * SS + SS + s];
        }
        xs[t] = make_float4(x0, x1, yv, 0.f);
    }

    // combine previous iteration's half-partials (fixed order -> deterministic)
    float X0 = 0.f, X1 = 0.f;
    if (iter > 0) {
        const float4* pp = (const float4*)(ws + WS_PART + ((iter - 1) * B + b) * 8);
        float4 p0 = pp[0], p1 = pp[1];
        float inv = __builtin_amdgcn_rcpf(p0.x + p1.x);
        X0 = (p0.y + p1.y) * inv;
        X1 = (p0.z + p1.z) * inv;
    }

    // per-lane register constants (4 h each)
    const int h4 = g * 4;
    float4 u;
    u = *(const float4*)(ws + 0 * HH + h4); const v2f a0_0 = {u.x, u.y}, a0_1 = {u.z, u.w};
    u = *(const float4*)(ws + 1 * HH + h4); const v2f a1_0 = {u.x, u.y}, a1_1 = {u.z, u.w};
    u = *(const float4*)(ws + 2 * HH + h4); const v2f ad_0 = {u.x, u.y}, ad_1 = {u.z, u.w};
    u = *(const float4*)(ws + 3 * HH + h4); const v2f vv_0 = {u.x, u.y}, vv_1 = {u.z, u.w};
    v2f cg_0, cg_1;
    if (iter == 0) {
        u = *(const float4*)(ws + 4 * HH + h4);
        cg_0 = (v2f){u.x, u.y};
        cg_1 = (v2f){u.z, u.w};
    } else {
        float4 ub = *(const float4*)(ws + 5 * HH + h4);
        float4 u0 = *(const float4*)(ws + 6 * HH + h4);
        float4 u1 = *(const float4*)(ws + 7 * HH + h4);
        v2f X0v = {X0, X0}, X1v = {X1, X1};
        cg_0 = __builtin_elementwise_fma(
            (v2f){u0.x, u0.y}, X0v,
            __builtin_elementwise_fma((v2f){u1.x, u1.y}, X1v, (v2f){ub.x, ub.y}));
        cg_1 = __builtin_elementwise_fma(
            (v2f){u0.z, u0.w}, X0v,
            __builtin_elementwise_fma((v2f){u1.z, u1.w}, X1v, (v2f){ub.z, ub.w}));
    }
    const float c01 = vv_0.x + vv_0.y;
    const float c23 = vv_1.x + vv_1.y;
    const float svc2 = ws[8 * HH];
    const v2f clampv = {24.f, 24.f};   // tanh clamp err ~1e-7; den products <= 2^100
    const bool owner = (g == 31);

    __syncthreads();  // xs ready

    float S = 0.f, Sx0 = 0.f, Sx1 = 0.f;
    #pragma unroll 4
    for (int pass = 0; pass < 16; ++pass) {
        const int sl = pass * 32 + sg;
        float4 x = xs[sl];
        v2f vx0 = {x.x, x.x}, vx1 = {x.y, x.y}, vyv = {x.z, x.z};
        v2f z0 = __builtin_elementwise_fma(
            a0_0, vx0, __builtin_elementwise_fma(
                a1_0, vx1, __builtin_elementwise_fma(ad_0, vyv, cg_0)));
        v2f z1 = __builtin_elementwise_fma(
            a0_1, vx0, __builtin_elementwise_fma(
                a1_1, vx1, __builtin_elementwise_fma(ad_1, vyv, cg_1)));
        z0 = __builtin_elementwise_min(z0, clampv);
        z1 = __builtin_elementwise_min(z1, clampv);
        float e0 = __builtin_amdgcn_exp2f(z0.x);
        float e1 = __builtin_amdgcn_exp2f(z0.y);
        float e2 = __builtin_amdgcn_exp2f(z1.x);
        float e3 = __builtin_amdgcn_exp2f(z1.y);
        // 4 sigmoids, one rcp
        float t1  = 1.f + e1, t3 = 1.f + e3;
        float d01 = fmaf(e0, t1, t1);
        float d23 = fmaf(e2, t3, t3);
        float n01 = fmaf(vv_0.x, e1, fmaf(vv_0.y, e0, c01));
        float n23 = fmaf(vv_1.x, e3, fmaf(vv_1.y, e2, c23));
        float num = fmaf(n01, d23, n23 * d01);
        float acc = num * __builtin_amdgcn_rcpf(d01 * d23);
        // 32-lane group sum -> lanes 31 / 63
        acc = dpp_add<0x111>(acc);
        acc = dpp_add<0x112>(acc);
        acc = dpp_add<0x114>(acc);
        acc = dpp_add<0x118>(acc);
        acc = dpp_add<0x142>(acc);
        const bool own = owner && (sl < NSH);
        float arg = own ? fmaf(-C1, acc, svc2) : -200.f;  // exp2(-200) == +0
        float pe = __builtin_amdgcn_exp2f(arg);
        S   += pe;
        Sx0  = fmaf(pe, x.x, Sx0);
        Sx1  = fmaf(pe, x.y, Sx1);
    }
    // owners at lanes 31,63 (others carry exact zeros)
    S   += __shfl_xor(S, 32);
    Sx0 += __shfl_xor(Sx0, 32);
    Sx1 += __shfl_xor(Sx1, 32);
    if (lane == 31) red4[t >> 6] = make_float4(S, Sx0, Sx1, 0.f);
    __syncthreads();
    float4 w4 = red4[lane & 15];
    #pragma unroll
    for (int off = 1; off < 16; off <<= 1) {
        w4.x += __shfl_xor(w4.x, off);
        w4.y += __shfl_xor(w4.y, off);
        w4.z += __shfl_xor(w4.z, off);
    }
    if (t == 0)
        *(float4*)(ws + WS_PART + ((iter * B + b) * 2 + half) * 4) =
            make_float4(w4.x, w4.y, w4.z, 0.f);
}

// ---- epilogue: grid B x 128 ----
__global__ __launch_bounds__(128) void sc_epi(
    const float* __restrict__ enc_s_w, const float* __restrict__ enc_s_b,
    const float* __restrict__ dense_w, const float* __restrict__ dense_b,
    const float* __restrict__ lin_w, const float* __restrict__ lin_b,
    const float* __restrict__ ws, int B, float* __restrict__ out) {
    const int b = blockIdx.x;
    const int t = threadIdx.x;
    __shared__ __align__(16) float hy_sh[HH];
    __shared__ float red[2];

    const float4* pp = (const float4*)(ws + WS_PART + (2 * B + b) * 8);
    float4 p0 = pp[0], p1 = pp[1];
    float inv = __builtin_amdgcn_rcpf(p0.x + p1.x);
    const float X0 = (p0.y + p1.y) * inv;
    const float X1 = (p0.z + p1.z) * inv;

    hy_sh[t] = fmaf(enc_s_w[2 * t], X0, fmaf(enc_s_w[2 * t + 1], X1, enc_s_b[t]));
    __syncthreads();

    const float4* dw4 = (const float4*)(dense_w + t * HH);
    const float4* hy4 = (const float4*)hy_sh;
    float r = dense_b[t];
    #pragma unroll 4
    for (int k = 0; k < HH / 4; ++k) {
        float4 d4 = dw4[k], h4 = hy4[k];
        r = fmaf(d4.x, h4.x, fmaf(d4.y, h4.y, fmaf(d4.z, h4.z, fmaf(d4.w, h4.w, r))));
    }
    float o = lin_w[t] * fmaxf(r, 0.f);
    #pragma unroll
    for (int off = 32; off > 0; off >>= 1) o += __shfl_xor(o, off);
    if ((t & 63) == 0) red[t >> 6] = o;
    __syncthreads();
    if (t == 0) out[b] = red[0] + red[1] + lin_b[0];
}

extern "C" void kernel_launch(void* const* d_in, const int* in_sizes, int n_in,
                              void* d_out, int out_size, void* d_ws, size_t ws_size,
                              hipStream_t stream) {
    const float* stat    = (const float*)d_in[0];
    const float* dyn     = (const float*)d_in[1];
    const float* enc_s_w = (const float*)d_in[2];
    const float* enc_s_b = (const float*)d_in[3];
    const float* enc_d_w = (const float*)d_in[4];
    const float* enc_d_b = (const float*)d_in[5];
    const float* v       = (const float*)d_in[6];
    const float* W       = (const float*)d_in[7];
    const float* dense_w = (const float*)d_in[8];
    const float* dense_b = (const float*)d_in[9];
    const float* lin_w   = (const float*)d_in[10];
    const float* lin_b   = (const float*)d_in[11];
    float* out = (float*)d_out;
    float* ws  = (float*)d_ws;

    const int B = in_sizes[0] / (2 * SS);

    hipLaunchKernelGGL(sc_fold, dim3(4), dim3(NT), 0, stream,
                       enc_s_w, enc_s_b, enc_d_w, enc_d_b, v, W, ws);
    for (int it = 0; it < 3; ++it)
        hipLaunchKernelGGL(sc_iter, dim3(2 * B), dim3(NT), 0, stream,
                           stat, dyn, ws, B, it);
    hipLaunchKernelGGL(sc_epi, dim3(B), dim3(128), 0, stream,
                       enc_s_w, enc_s_b, dense_w, dense_b, lin_w, lin_b, ws, B, out);
}

// Round 11
// 40.986 us; speedup vs baseline: 1.3537x; 1.3222x over previous
//
#include <hip/hip_runtime.h>
#include <math.h>

#define HH  128   // hidden size
#define SS  1000  // sequence length
#define NT  1024  // threads per block (16 waves)
#define NW  (NT / 64)
#define C1 2.8853900817779268f  // 2*log2(e)
#define C2 1.4426950408889634f  // log2(e)

typedef float v2f __attribute__((ext_vector_type(2)));

// DPP adds: row_shr:N sums within 16-lane rows toward lane 15; row_bcast15
// (0x142) completes 32-lane sums at lanes 31/63. Verified absmax-0 in R8/R10.
template <int CTRL>
__device__ __forceinline__ float dpp_add(float x) {
    int s = __builtin_amdgcn_update_dpp(0, __builtin_bit_cast(int, x),
                                        CTRL, 0xF, 0xF, true);
    return x + __builtin_bit_cast(float, s);
}

// ws float layout: [0..1024) kc rows 0..7 (row*128+h):
//   0:a0*C1 1:a1*C1 2:ad*C1 3:v 4:cc*C1 5:(cc+w3b)*C1 6:w30*C1 7:w31*C1
// [1024] svc2 = sum(v)*log2(e)

// ---- fold kernel: grid 4 x 1024 (verbatim from R10, verified) ----
__global__ __launch_bounds__(NT) void sc_fold(
    const float* __restrict__ enc_s_w, const float* __restrict__ enc_s_b,
    const float* __restrict__ enc_d_w, const float* __restrict__ enc_d_b,
    const float* __restrict__ v, const float* __restrict__ W,
    float* __restrict__ ws) {
    const int t  = threadIdx.x;
    const int fh = blockIdx.x * 32 + (t >> 5);
    const int fq = t & 31;
    const float4* W1 = (const float4*)(W + fh * (3 * HH));
    const float4* W2 = (const float4*)(W + fh * (3 * HH) + HH);
    const float4* W3 = (const float4*)(W + fh * (3 * HH) + 2 * HH);
    const float4* ES = (const float4*)enc_s_w;
    const float4* ED = (const float4*)enc_d_w;
    const float4* SB = (const float4*)enc_s_b;
    const float4* DB = (const float4*)enc_d_b;
    const int k4 = fq;
    float4 w1 = W1[k4], w2 = W2[k4], w3 = W3[k4];
    float4 e01 = ES[2 * k4], e23 = ES[2 * k4 + 1];
    float4 d01 = ED[2 * k4], d23 = ED[2 * k4 + 1];
    float4 sb = SB[k4], db = DB[k4];
    float a0 = 0.f, a1 = 0.f, ad = 0.f, cc = 0.f, w30 = 0.f, w31 = 0.f, w3b = 0.f;
    a0 = fmaf(w1.x, e01.x, a0); a0 = fmaf(w1.y, e01.z, a0);
    a0 = fmaf(w1.z, e23.x, a0); a0 = fmaf(w1.w, e23.z, a0);
    a1 = fmaf(w1.x, e01.y, a1); a1 = fmaf(w1.y, e01.w, a1);
    a1 = fmaf(w1.z, e23.y, a1); a1 = fmaf(w1.w, e23.w, a1);
    ad = fmaf(w2.x, d01.x + d01.y, ad); ad = fmaf(w2.y, d01.z + d01.w, ad);
    ad = fmaf(w2.z, d23.x + d23.y, ad); ad = fmaf(w2.w, d23.z + d23.w, ad);
    cc = fmaf(w1.x, sb.x, cc); cc = fmaf(w1.y, sb.y, cc);
    cc = fmaf(w1.z, sb.z, cc); cc = fmaf(w1.w, sb.w, cc);
    cc = fmaf(w2.x, db.x, cc); cc = fmaf(w2.y, db.y, cc);
    cc = fmaf(w2.z, db.z, cc); cc = fmaf(w2.w, db.w, cc);
    w30 = fmaf(w3.x, e01.x, w30); w30 = fmaf(w3.y, e01.z, w30);
    w30 = fmaf(w3.z, e23.x, w30); w30 = fmaf(w3.w, e23.z, w30);
    w31 = fmaf(w3.x, e01.y, w31); w31 = fmaf(w3.y, e01.w, w31);
    w31 = fmaf(w3.z, e23.y, w31); w31 = fmaf(w3.w, e23.w, w31);
    w3b = fmaf(w3.x, sb.x, w3b); w3b = fmaf(w3.y, sb.y, w3b);
    w3b = fmaf(w3.z, sb.z, w3b); w3b = fmaf(w3.w, sb.w, w3b);
    a0  = dpp_add<0x111>(a0);  a0  = dpp_add<0x112>(a0);  a0  = dpp_add<0x114>(a0);
    a0  = dpp_add<0x118>(a0);  a0  = dpp_add<0x142>(a0);
    a1  = dpp_add<0x111>(a1);  a1  = dpp_add<0x112>(a1);  a1  = dpp_add<0x114>(a1);
    a1  = dpp_add<0x118>(a1);  a1  = dpp_add<0x142>(a1);
    ad  = dpp_add<0x111>(ad);  ad  = dpp_add<0x112>(ad);  ad  = dpp_add<0x114>(ad);
    ad  = dpp_add<0x118>(ad);  ad  = dpp_add<0x142>(ad);
    cc  = dpp_add<0x111>(cc);  cc  = dpp_add<0x112>(cc);  cc  = dpp_add<0x114>(cc);
    cc  = dpp_add<0x118>(cc);  cc  = dpp_add<0x142>(cc);
    w30 = dpp_add<0x111>(w30); w30 = dpp_add<0x112>(w30); w30 = dpp_add<0x114>(w30);
    w30 = dpp_add<0x118>(w30); w30 = dpp_add<0x142>(w30);
    w31 = dpp_add<0x111>(w31); w31 = dpp_add<0x112>(w31); w31 = dpp_add<0x114>(w31);
    w31 = dpp_add<0x118>(w31); w31 = dpp_add<0x142>(w31);
    w3b = dpp_add<0x111>(w3b); w3b = dpp_add<0x112>(w3b); w3b = dpp_add<0x114>(w3b);
    w3b = dpp_add<0x118>(w3b); w3b = dpp_add<0x142>(w3b);
    if (fq == 31) {
        ws[0 * HH + fh] = a0 * C1;
        ws[1 * HH + fh] = a1 * C1;
        ws[2 * HH + fh] = ad * C1;
        ws[4 * HH + fh] = cc * C1;
        ws[5 * HH + fh] = (cc + w3b) * C1;
        ws[6 * HH + fh] = w30 * C1;
        ws[7 * HH + fh] = w31 * C1;
    }
    if (blockIdx.x == 0) {
        if (t < HH) ws[3 * HH + t] = v[t];
        if (t < 32) {
            float4 x = ((const float4*)v)[t];
            float s = (x.x + x.y) + (x.z + x.w);
            #pragma unroll
            for (int off = 1; off < 32; off <<= 1) s += __shfl_xor(s, off);
            if (t == 0) ws[8 * HH] = s * C2;
        }
    }
}

// ---- main kernel: grid B x 1024, one block per batch ----
// 8 h per thread (16-lane h-groups), constants register-resident, 1 rcp per
// 8 sigmoids (clamp 14 -> d_oct <= 2^112), explicit 2-deep xs prefetch.
__global__ __launch_bounds__(NT, 4) void sc_main(
    const float* __restrict__ stat, const float* __restrict__ dyn,
    const float* __restrict__ ws,
    const float* __restrict__ enc_s_w, const float* __restrict__ enc_s_b,
    const float* __restrict__ dense_w, const float* __restrict__ dense_b,
    const float* __restrict__ lin_w, const float* __restrict__ lin_b,
    float* __restrict__ out) {
    const int b    = blockIdx.x;
    const int t    = threadIdx.x;
    const int wave = t >> 6;
    const int lane = t & 63;
    const int gl   = t & 15;   // lane-in-group; h = gl*8 .. gl*8+7
    const int sg   = t >> 4;   // s-group 0..63; s = pass*64 + sg

    __shared__ __align__(16) float4 xs[NT];
    __shared__ float4 red4[2][NW];
    __shared__ float hy_sh[HH];

    // stage per-s inputs (coalesced)
    {
        float x0 = 0.f, x1 = 0.f, yv = 0.f;
        if (t < SS) {
            const float* sbp = stat + (size_t)b * 2 * SS;
            x0 = sbp[t];
            x1 = sbp[SS + t];
            yv = dyn[(size_t)b * 2 * SS + SS + t];
        }
        xs[t] = make_float4(x0, x1, yv, 0.f);
    }

    // register-resident constants: 8 h x {a0,a1,ad,v} = 16 v2f
    const int h0 = gl * 8;
    float4 u, u2;
    u = *(const float4*)(ws + 0 * HH + h0); u2 = *(const float4*)(ws + 0 * HH + h0 + 4);
    const v2f a0_0 = {u.x, u.y},  a0_1 = {u.z, u.w},
              a0_2 = {u2.x, u2.y}, a0_3 = {u2.z, u2.w};
    u = *(const float4*)(ws + 1 * HH + h0); u2 = *(const float4*)(ws + 1 * HH + h0 + 4);
    const v2f a1_0 = {u.x, u.y},  a1_1 = {u.z, u.w},
              a1_2 = {u2.x, u2.y}, a1_3 = {u2.z, u2.w};
    u = *(const float4*)(ws + 2 * HH + h0); u2 = *(const float4*)(ws + 2 * HH + h0 + 4);
    const v2f ad_0 = {u.x, u.y},  ad_1 = {u.z, u.w},
              ad_2 = {u2.x, u2.y}, ad_3 = {u2.z, u2.w};
    u = *(const float4*)(ws + 3 * HH + h0); u2 = *(const float4*)(ws + 3 * HH + h0 + 4);
    const v2f vv_0 = {u.x, u.y},  vv_1 = {u.z, u.w},
              vv_2 = {u2.x, u2.y}, vv_3 = {u2.z, u2.w};
    const float cp0 = vv_0.x + vv_0.y, cp1 = vv_1.x + vv_1.y;
    const float cp2 = vv_2.x + vv_2.y, cp3 = vv_3.x + vv_3.y;
    const float svc2 = ws[8 * HH];
    const v2f clampv = {14.f, 14.f};   // e<=2^14 -> oct denominator <= 2^112
    const bool ownerBase = (gl == 15);

    __syncthreads();  // xs ready

    float X0 = 0.f, X1 = 0.f;

    for (int iter = 0; iter < 3; ++iter) {
        // per-iter bias (4 v2f)
        v2f cg_0, cg_1, cg_2, cg_3;
        if (iter == 0) {
            u = *(const float4*)(ws + 4 * HH + h0);
            u2 = *(const float4*)(ws + 4 * HH + h0 + 4);
            cg_0 = (v2f){u.x, u.y};  cg_1 = (v2f){u.z, u.w};
            cg_2 = (v2f){u2.x, u2.y}; cg_3 = (v2f){u2.z, u2.w};
        } else {
            float4 b1 = *(const float4*)(ws + 5 * HH + h0);
            float4 b2 = *(const float4*)(ws + 5 * HH + h0 + 4);
            float4 p1 = *(const float4*)(ws + 6 * HH + h0);
            float4 p2 = *(const float4*)(ws + 6 * HH + h0 + 4);
            float4 q1 = *(const float4*)(ws + 7 * HH + h0);
            float4 q2 = *(const float4*)(ws + 7 * HH + h0 + 4);
            v2f X0v = {X0, X0}, X1v = {X1, X1};
            cg_0 = __builtin_elementwise_fma(
                (v2f){p1.x, p1.y}, X0v,
                __builtin_elementwise_fma((v2f){q1.x, q1.y}, X1v, (v2f){b1.x, b1.y}));
            cg_1 = __builtin_elementwise_fma(
                (v2f){p1.z, p1.w}, X0v,
                __builtin_elementwise_fma((v2f){q1.z, q1.w}, X1v, (v2f){b1.z, b1.w}));
            cg_2 = __builtin_elementwise_fma(
                (v2f){p2.x, p2.y}, X0v,
                __builtin_elementwise_fma((v2f){q2.x, q2.y}, X1v, (v2f){b2.x, b2.y}));
            cg_3 = __builtin_elementwise_fma(
                (v2f){p2.z, p2.w}, X0v,
                __builtin_elementwise_fma((v2f){q2.z, q2.w}, X1v, (v2f){b2.z, b2.w}));
        }

        float S = 0.f, Sx0 = 0.f, Sx1 = 0.f;
        float4 xC = xs[sg];   // pass-0 data, prefetched before the loop
        #pragma unroll 4
        for (int pass = 0; pass < 16; ++pass) {
            // prefetch next pass (wraps harmlessly on the last)
            float4 xN = xs[((pass + 1) & 15) * 64 + sg];
            const int s = pass * 64 + sg;
            v2f vx0 = {xC.x, xC.x}, vx1 = {xC.y, xC.y}, vyv = {xC.z, xC.z};
            v2f z0 = __builtin_elementwise_fma(a0_0, vx0,
                     __builtin_elementwise_fma(a1_0, vx1,
                     __builtin_elementwise_fma(ad_0, vyv, cg_0)));
            v2f z1 = __builtin_elementwise_fma(a0_1, vx0,
                     __builtin_elementwise_fma(a1_1, vx1,
                     __builtin_elementwise_fma(ad_1, vyv, cg_1)));
            v2f z2 = __builtin_elementwise_fma(a0_2, vx0,
                     __builtin_elementwise_fma(a1_2, vx1,
                     __builtin_elementwise_fma(ad_2, vyv, cg_2)));
            v2f z3 = __builtin_elementwise_fma(a0_3, vx0,
                     __builtin_elementwise_fma(a1_3, vx1,
                     __builtin_elementwise_fma(ad_3, vyv, cg_3)));
            z0 = __builtin_elementwise_min(z0, clampv);
            z1 = __builtin_elementwise_min(z1, clampv);
            z2 = __builtin_elementwise_min(z2, clampv);
            z3 = __builtin_elementwise_min(z3, clampv);
            float e0 = __builtin_amdgcn_exp2f(z0.x);
            float e1 = __builtin_amdgcn_exp2f(z0.y);
            float e2 = __builtin_amdgcn_exp2f(z1.x);
            float e3 = __builtin_amdgcn_exp2f(z1.y);
            float e4 = __builtin_amdgcn_exp2f(z2.x);
            float e5 = __builtin_amdgcn_exp2f(z2.y);
            float e6 = __builtin_amdgcn_exp2f(z3.x);
            float e7 = __builtin_amdgcn_exp2f(z3.y);
            // pair combine: va/(1+ea)+vb/(1+eb) = (cp + va*eb + vb*ea)/((1+ea)(1+eb))
            float tb0 = 1.f + e1, tb1 = 1.f + e3, tb2 = 1.f + e5, tb3 = 1.f + e7;
            float d0 = fmaf(e0, tb0, tb0);
            float d1 = fmaf(e2, tb1, tb1);
            float d2 = fmaf(e4, tb2, tb2);
            float d3 = fmaf(e6, tb3, tb3);
            float n0 = fmaf(vv_0.x, e1, fmaf(vv_0.y, e0, cp0));
            float n1 = fmaf(vv_1.x, e3, fmaf(vv_1.y, e2, cp1));
            float n2 = fmaf(vv_2.x, e5, fmaf(vv_2.y, e4, cp2));
            float n3 = fmaf(vv_3.x, e7, fmaf(vv_3.y, e6, cp3));
            // quads
            float Nq0 = fmaf(n0, d1, n1 * d0), Dq0 = d0 * d1;
            float Nq1 = fmaf(n2, d3, n3 * d2), Dq1 = d2 * d3;
            // oct: ONE rcp for 8 sigmoids
            float Noc = fmaf(Nq0, Dq1, Nq1 * Dq0);
            float acc = Noc * __builtin_amdgcn_rcpf(Dq0 * Dq1);
            // 16-lane group sum -> lane gl==15
            acc = dpp_add<0x111>(acc);
            acc = dpp_add<0x112>(acc);
            acc = dpp_add<0x114>(acc);
            acc = dpp_add<0x118>(acc);
            const bool own = ownerBase && (s < SS);
            float arg = own ? fmaf(-C1, acc, svc2) : -200.f;  // exp2(-200)==+0
            float p = __builtin_amdgcn_exp2f(arg);
            S   += p;
            Sx0  = fmaf(p, xC.x, Sx0);
            Sx1  = fmaf(p, xC.y, Sx1);
            xC = xN;
        }
        // owners at lanes 15,31,47,63 (others carry exact zeros)
        S   += __shfl_xor(S, 16);   S   += __shfl_xor(S, 32);
        Sx0 += __shfl_xor(Sx0, 16); Sx0 += __shfl_xor(Sx0, 32);
        Sx1 += __shfl_xor(Sx1, 16); Sx1 += __shfl_xor(Sx1, 32);
        if (lane == 15) red4[iter & 1][wave] = make_float4(S, Sx0, Sx1, 0.f);
        __syncthreads();  // only barrier per iteration
        float4 w4 = red4[iter & 1][lane & 15];
        #pragma unroll
        for (int off = 1; off < 16; off <<= 1) {
            w4.x += __shfl_xor(w4.x, off);
            w4.y += __shfl_xor(w4.y, off);
            w4.z += __shfl_xor(w4.z, off);
        }
        float inv = __builtin_amdgcn_rcpf(w4.x);
        X0 = w4.y * inv;  // uniform across block
        X1 = w4.z * inv;
    }

    // hy[h] = enc_s_w[h,0]*X0 + enc_s_w[h,1]*X1 + enc_s_b[h]
    if (t < HH)
        hy_sh[t] = fmaf(enc_s_w[2 * t], X0, fmaf(enc_s_w[2 * t + 1], X1, enc_s_b[t]));
    __syncthreads();

    // out[b] = lin_w @ relu(dense_w @ hy + dense_b) + lin_b
    float o = 0.f;
    if (t < HH) {
        const float4* dw4 = (const float4*)(dense_w + t * HH);
        const float4* hy4 = (const float4*)hy_sh;
        float r = dense_b[t];
        #pragma unroll 4
        for (int k = 0; k < HH / 4; ++k) {
            float4 d4 = dw4[k], h4v = hy4[k];
            r = fmaf(d4.x, h4v.x, fmaf(d4.y, h4v.y, fmaf(d4.z, h4v.z, fmaf(d4.w, h4v.w, r))));
        }
        o = lin_w[t] * fmaxf(r, 0.f);
    }
    #pragma unroll
    for (int off = 32; off > 0; off >>= 1) o += __shfl_xor(o, off);
    if (lane == 0) red4[0][wave].x = o;
    __syncthreads();
    if (t == 0) {
        float s = 0.f;
        for (int i = 0; i < NW; ++i) s += red4[0][i].x;
        out[b] = s + lin_b[0];
    }
}

extern "C" void kernel_launch(void* const* d_in, const int* in_sizes, int n_in,
                              void* d_out, int out_size, void* d_ws, size_t ws_size,
                              hipStream_t stream) {
    const float* stat    = (const float*)d_in[0];
    const float* dyn     = (const float*)d_in[1];
    const float* enc_s_w = (const float*)d_in[2];
    const float* enc_s_b = (const float*)d_in[3];
    const float* enc_d_w = (const float*)d_in[4];
    const float* enc_d_b = (const float*)d_in[5];
    const float* v       = (const float*)d_in[6];
    const float* W       = (const float*)d_in[7];
    const float* dense_w = (const float*)d_in[8];
    const float* dense_b = (const float*)d_in[9];
    const float* lin_w   = (const float*)d_in[10];
    const float* lin_b   = (const float*)d_in[11];
    float* out = (float*)d_out;
    float* ws  = (float*)d_ws;

    const int B = in_sizes[0] / (2 * SS);

    hipLaunchKernelGGL(sc_fold, dim3(4), dim3(NT), 0, stream,
                       enc_s_w, enc_s_b, enc_d_w, enc_d_b, v, W, ws);
    hipLaunchKernelGGL(sc_main, dim3(B), dim3(NT), 0, stream,
                       stat, dyn, ws, enc_s_w, enc_s_b, dense_w, dense_b,
                       lin_w, lin_b, out);
}

// Round 13
// 40.724 us; speedup vs baseline: 1.3624x; 1.0064x over previous
//
#include <hip/hip_runtime.h>
#include <math.h>

#define HH  128   // hidden size
#define SS  1000  // sequence length
#define NT  1024  // threads per block (16 waves)
#define NW  (NT / 64)
#define C1 2.8853900817779268f  // 2*log2(e)
#define C2 1.4426950408889634f  // log2(e)

typedef float v2f __attribute__((ext_vector_type(2)));

// DPP adds: row_shr:N suffix-sums within 16-lane rows toward lane 15.
// Verified absmax-0 in R8/R10/R11.
template <int CTRL>
__device__ __forceinline__ float dpp_add(float x) {
    int s = __builtin_amdgcn_update_dpp(0, __builtin_bit_cast(int, x),
                                        CTRL, 0xF, 0xF, true);
    return x + __builtin_bit_cast(float, s);
}

// ws float layout: [0..1024) kc rows 0..7 (row*128+h):
//   0:a0*C1 1:a1*C1 2:ad*C1 3:v 4:cc*C1 5:(cc+w3b)*C1 6:w30*C1 7:w31*C1
// [1024] svc2 = sum(v)*log2(e)

// ---- fold kernel: grid 4 x 1024 (verbatim from R10/R11, verified) ----
__global__ __launch_bounds__(NT) void sc_fold(
    const float* __restrict__ enc_s_w, const float* __restrict__ enc_s_b,
    const float* __restrict__ enc_d_w, const float* __restrict__ enc_d_b,
    const float* __restrict__ v, const float* __restrict__ W,
    float* __restrict__ ws) {
    const int t  = threadIdx.x;
    const int fh = blockIdx.x * 32 + (t >> 5);
    const int fq = t & 31;
    const float4* W1 = (const float4*)(W + fh * (3 * HH));
    const float4* W2 = (const float4*)(W + fh * (3 * HH) + HH);
    const float4* W3 = (const float4*)(W + fh * (3 * HH) + 2 * HH);
    const float4* ES = (const float4*)enc_s_w;
    const float4* ED = (const float4*)enc_d_w;
    const float4* SB = (const float4*)enc_s_b;
    const float4* DB = (const float4*)enc_d_b;
    const int k4 = fq;
    float4 w1 = W1[k4], w2 = W2[k4], w3 = W3[k4];
    float4 e01 = ES[2 * k4], e23 = ES[2 * k4 + 1];
    float4 d01 = ED[2 * k4], d23 = ED[2 * k4 + 1];
    float4 sb = SB[k4], db = DB[k4];
    float a0 = 0.f, a1 = 0.f, ad = 0.f, cc = 0.f, w30 = 0.f, w31 = 0.f, w3b = 0.f;
    a0 = fmaf(w1.x, e01.x, a0); a0 = fmaf(w1.y, e01.z, a0);
    a0 = fmaf(w1.z, e23.x, a0); a0 = fmaf(w1.w, e23.z, a0);
    a1 = fmaf(w1.x, e01.y, a1); a1 = fmaf(w1.y, e01.w, a1);
    a1 = fmaf(w1.z, e23.y, a1); a1 = fmaf(w1.w, e23.w, a1);
    ad = fmaf(w2.x, d01.x + d01.y, ad); ad = fmaf(w2.y, d01.z + d01.w, ad);
    ad = fmaf(w2.z, d23.x + d23.y, ad); ad = fmaf(w2.w, d23.z + d23.w, ad);
    cc = fmaf(w1.x, sb.x, cc); cc = fmaf(w1.y, sb.y, cc);
    cc = fmaf(w1.z, sb.z, cc); cc = fmaf(w1.w, sb.w, cc);
    cc = fmaf(w2.x, db.x, cc); cc = fmaf(w2.y, db.y, cc);
    cc = fmaf(w2.z, db.z, cc); cc = fmaf(w2.w, db.w, cc);
    w30 = fmaf(w3.x, e01.x, w30); w30 = fmaf(w3.y, e01.z, w30);
    w30 = fmaf(w3.z, e23.x, w30); w30 = fmaf(w3.w, e23.z, w30);
    w31 = fmaf(w3.x, e01.y, w31); w31 = fmaf(w3.y, e01.w, w31);
    w31 = fmaf(w3.z, e23.y, w31); w31 = fmaf(w3.w, e23.w, w31);
    w3b = fmaf(w3.x, sb.x, w3b); w3b = fmaf(w3.y, sb.y, w3b);
    w3b = fmaf(w3.z, sb.z, w3b); w3b = fmaf(w3.w, sb.w, w3b);
    a0  = dpp_add<0x111>(a0);  a0  = dpp_add<0x112>(a0);  a0  = dpp_add<0x114>(a0);
    a0  = dpp_add<0x118>(a0);  a0  = dpp_add<0x142>(a0);
    a1  = dpp_add<0x111>(a1);  a1  = dpp_add<0x112>(a1);  a1  = dpp_add<0x114>(a1);
    a1  = dpp_add<0x118>(a1);  a1  = dpp_add<0x142>(a1);
    ad  = dpp_add<0x111>(ad);  ad  = dpp_add<0x112>(ad);  ad  = dpp_add<0x114>(ad);
    ad  = dpp_add<0x118>(ad);  ad  = dpp_add<0x142>(ad);
    cc  = dpp_add<0x111>(cc);  cc  = dpp_add<0x112>(cc);  cc  = dpp_add<0x114>(cc);
    cc  = dpp_add<0x118>(cc);  cc  = dpp_add<0x142>(cc);
    w30 = dpp_add<0x111>(w30); w30 = dpp_add<0x112>(w30); w30 = dpp_add<0x114>(w30);
    w30 = dpp_add<0x118>(w30); w30 = dpp_add<0x142>(w30);
    w31 = dpp_add<0x111>(w31); w31 = dpp_add<0x112>(w31); w31 = dpp_add<0x114>(w31);
    w31 = dpp_add<0x118>(w31); w31 = dpp_add<0x142>(w31);
    w3b = dpp_add<0x111>(w3b); w3b = dpp_add<0x112>(w3b); w3b = dpp_add<0x114>(w3b);
    w3b = dpp_add<0x118>(w3b); w3b = dpp_add<0x142>(w3b);
    if (fq == 31) {
        ws[0 * HH + fh] = a0 * C1;
        ws[1 * HH + fh] = a1 * C1;
        ws[2 * HH + fh] = ad * C1;
        ws[4 * HH + fh] = cc * C1;
        ws[5 * HH + fh] = (cc + w3b) * C1;
        ws[6 * HH + fh] = w30 * C1;
        ws[7 * HH + fh] = w31 * C1;
    }
    if (blockIdx.x == 0) {
        if (t < HH) ws[3 * HH + t] = v[t];
        if (t < 32) {
            float4 x = ((const float4*)v)[t];
            float s = (x.x + x.y) + (x.z + x.w);
            #pragma unroll
            for (int off = 1; off < 32; off <<= 1) s += __shfl_xor(s, off);
            if (t == 0) ws[8 * HH] = s * C2;
        }
    }
}

// 8-sigmoid octet with ONE rcp (verified R11): returns group-partial acc.
#define OCTET(X, ACC)                                                         \
    {                                                                         \
        v2f vx0 = {X.x, X.x}, vx1 = {X.y, X.y}, vyv = {X.z, X.z};             \
        v2f z0 = __builtin_elementwise_fma(a0_0, vx0,                         \
                 __builtin_elementwise_fma(a1_0, vx1,                         \
                 __builtin_elementwise_fma(ad_0, vyv, cg_0)));                \
        v2f z1 = __builtin_elementwise_fma(a0_1, vx0,                         \
                 __builtin_elementwise_fma(a1_1, vx1,                         \
                 __builtin_elementwise_fma(ad_1, vyv, cg_1)));                \
        v2f z2 = __builtin_elementwise_fma(a0_2, vx0,                         \
                 __builtin_elementwise_fma(a1_2, vx1,                         \
                 __builtin_elementwise_fma(ad_2, vyv, cg_2)));                \
        v2f z3 = __builtin_elementwise_fma(a0_3, vx0,                         \
                 __builtin_elementwise_fma(a1_3, vx1,                         \
                 __builtin_elementwise_fma(ad_3, vyv, cg_3)));                \
        z0 = __builtin_elementwise_min(z0, clampv);                           \
        z1 = __builtin_elementwise_min(z1, clampv);                           \
        z2 = __builtin_elementwise_min(z2, clampv);                           \
        z3 = __builtin_elementwise_min(z3, clampv);                           \
        float e0 = __builtin_amdgcn_exp2f(z0.x);                              \
        float e1 = __builtin_amdgcn_exp2f(z0.y);                              \
        float e2 = __builtin_amdgcn_exp2f(z1.x);                              \
        float e3 = __builtin_amdgcn_exp2f(z1.y);                              \
        float e4 = __builtin_amdgcn_exp2f(z2.x);                              \
        float e5 = __builtin_amdgcn_exp2f(z2.y);                              \
        float e6 = __builtin_amdgcn_exp2f(z3.x);                              \
        float e7 = __builtin_amdgcn_exp2f(z3.y);                              \
        float tb0 = 1.f + e1, tb1 = 1.f + e3, tb2 = 1.f + e5, tb3 = 1.f + e7; \
        float d0 = fmaf(e0, tb0, tb0);                                        \
        float d1 = fmaf(e2, tb1, tb1);                                        \
        float d2 = fmaf(e4, tb2, tb2);                                        \
        float d3 = fmaf(e6, tb3, tb3);                                        \
        float n0 = fmaf(vv_0.x, e1, fmaf(vv_0.y, e0, cp0));                   \
        float n1 = fmaf(vv_1.x, e3, fmaf(vv_1.y, e2, cp1));                   \
        float n2 = fmaf(vv_2.x, e5, fmaf(vv_2.y, e4, cp2));                   \
        float n3 = fmaf(vv_3.x, e7, fmaf(vv_3.y, e6, cp3));                   \
        float Nq0 = fmaf(n0, d1, n1 * d0), Dq0 = d0 * d1;                     \
        float Nq1 = fmaf(n2, d3, n3 * d2), Dq1 = d2 * d3;                     \
        float Noc = fmaf(Nq0, Dq1, Nq1 * Dq0);                                \
        ACC = Noc * __builtin_amdgcn_rcpf(Dq0 * Dq1);                         \
        ACC = dpp_add<0x111>(ACC);                                            \
        ACC = dpp_add<0x112>(ACC);                                            \
        ACC = dpp_add<0x114>(ACC);                                            \
        ACC = dpp_add<0x118>(ACC);                                            \
    }

// ---- main kernel: grid B x 1024, 8 h/thread, 2 independent s per pass ----
__global__ __launch_bounds__(NT, 4) void sc_main(
    const float* __restrict__ stat, const float* __restrict__ dyn,
    const float* __restrict__ ws,
    const float* __restrict__ enc_s_w, const float* __restrict__ enc_s_b,
    const float* __restrict__ dense_w, const float* __restrict__ dense_b,
    const float* __restrict__ lin_w, const float* __restrict__ lin_b,
    float* __restrict__ out) {
    const int b    = blockIdx.x;
    const int t    = threadIdx.x;
    const int wave = t >> 6;
    const int lane = t & 63;
    const int gl   = t & 15;   // lane-in-group; h = gl*8 .. gl*8+7
    const int sg   = t >> 4;   // s-group 0..63

    __shared__ __align__(16) float4 xs[NT];
    __shared__ float4 red4[2][NW];
    __shared__ float hy_sh[HH];

    // stage per-s inputs (coalesced)
    {
        float x0 = 0.f, x1 = 0.f, yv = 0.f;
        if (t < SS) {
            const float* sbp = stat + (size_t)b * 2 * SS;
            x0 = sbp[t];
            x1 = sbp[SS + t];
            yv = dyn[(size_t)b * 2 * SS + SS + t];
        }
        xs[t] = make_float4(x0, x1, yv, 0.f);
    }

    // register-resident constants: 8 h x {a0,a1,ad,v} = 16 v2f (proven R11)
    const int h0 = gl * 8;
    float4 u, u2;
    u = *(const float4*)(ws + 0 * HH + h0); u2 = *(const float4*)(ws + 0 * HH + h0 + 4);
    const v2f a0_0 = {u.x, u.y},  a0_1 = {u.z, u.w},
              a0_2 = {u2.x, u2.y}, a0_3 = {u2.z, u2.w};
    u = *(const float4*)(ws + 1 * HH + h0); u2 = *(const float4*)(ws + 1 * HH + h0 + 4);
    const v2f a1_0 = {u.x, u.y},  a1_1 = {u.z, u.w},
              a1_2 = {u2.x, u2.y}, a1_3 = {u2.z, u2.w};
    u = *(const float4*)(ws + 2 * HH + h0); u2 = *(const float4*)(ws + 2 * HH + h0 + 4);
    const v2f ad_0 = {u.x, u.y},  ad_1 = {u.z, u.w},
              ad_2 = {u2.x, u2.y}, ad_3 = {u2.z, u2.w};
    u = *(const float4*)(ws + 3 * HH + h0); u2 = *(const float4*)(ws + 3 * HH + h0 + 4);
    const v2f vv_0 = {u.x, u.y},  vv_1 = {u.z, u.w},
              vv_2 = {u2.x, u2.y}, vv_3 = {u2.z, u2.w};
    const float cp0 = vv_0.x + vv_0.y, cp1 = vv_1.x + vv_1.y;
    const float cp2 = vv_2.x + vv_2.y, cp3 = vv_3.x + vv_3.y;
    const float svc2 = ws[8 * HH];
    const v2f clampv = {14.f, 14.f};   // e<=2^14: oct denominator <= 2^112
    const bool ownerBase = (gl == 15);

    __syncthreads();  // xs ready

    float X0 = 0.f, X1 = 0.f;

    for (int iter = 0; iter < 3; ++iter) {
        // per-iter bias (4 v2f)
        v2f cg_0, cg_1, cg_2, cg_3;
        if (iter == 0) {
            u = *(const float4*)(ws + 4 * HH + h0);
            u2 = *(const float4*)(ws + 4 * HH + h0 + 4);
            cg_0 = (v2f){u.x, u.y};  cg_1 = (v2f){u.z, u.w};
            cg_2 = (v2f){u2.x, u2.y}; cg_3 = (v2f){u2.z, u2.w};
        } else {
            float4 b1 = *(const float4*)(ws + 5 * HH + h0);
            float4 b2 = *(const float4*)(ws + 5 * HH + h0 + 4);
            float4 p1 = *(const float4*)(ws + 6 * HH + h0);
            float4 p2 = *(const float4*)(ws + 6 * HH + h0 + 4);
            float4 q1 = *(const float4*)(ws + 7 * HH + h0);
            float4 q2 = *(const float4*)(ws + 7 * HH + h0 + 4);
            v2f X0v = {X0, X0}, X1v = {X1, X1};
            cg_0 = __builtin_elementwise_fma(
                (v2f){p1.x, p1.y}, X0v,
                __builtin_elementwise_fma((v2f){q1.x, q1.y}, X1v, (v2f){b1.x, b1.y}));
            cg_1 = __builtin_elementwise_fma(
                (v2f){p1.z, p1.w}, X0v,
                __builtin_elementwise_fma((v2f){q1.z, q1.w}, X1v, (v2f){b1.z, b1.w}));
            cg_2 = __builtin_elementwise_fma(
                (v2f){p2.x, p2.y}, X0v,
                __builtin_elementwise_fma((v2f){q2.x, q2.y}, X1v, (v2f){b2.x, b2.y}));
            cg_3 = __builtin_elementwise_fma(
                (v2f){p2.z, p2.w}, X0v,
                __builtin_elementwise_fma((v2f){q2.z, q2.w}, X1v, (v2f){b2.z, b2.w}));
        }

        // two independent s-streams per pass: sA = pass*64+sg (always < 512,
        // valid), sB = 512 + pass*64+sg (valid iff < SS)
        float S = 0.f, Sx0 = 0.f, Sx1 = 0.f;
        #pragma unroll 2
        for (int pass = 0; pass < 8; ++pass) {
            const int sA = pass * 64 + sg;
            const int sB = 512 + sA;
            float4 xA = xs[sA];
            float4 xB = xs[sB];
            float accA, accB;
            OCTET(xA, accA);
            OCTET(xB, accB);
            float argA = ownerBase ? fmaf(-C1, accA, svc2) : -200.f;
            const bool ownB = ownerBase && (sB < SS);
            float argB = ownB ? fmaf(-C1, accB, svc2) : -200.f;
            float pA = __builtin_amdgcn_exp2f(argA);
            float pB = __builtin_amdgcn_exp2f(argB);
            S   += pA + pB;
            Sx0  = fmaf(pA, xA.x, fmaf(pB, xB.x, Sx0));
            Sx1  = fmaf(pA, xA.y, fmaf(pB, xB.y, Sx1));
        }
        // owners at lanes 15,31,47,63 (others carry exact zeros)
        S   += __shfl_xor(S, 16);   S   += __shfl_xor(S, 32);
        Sx0 += __shfl_xor(Sx0, 16); Sx0 += __shfl_xor(Sx0, 32);
        Sx1 += __shfl_xor(Sx1, 16); Sx1 += __shfl_xor(Sx1, 32);
        if (lane == 15) red4[iter & 1][wave] = make_float4(S, Sx0, Sx1, 0.f);
        __syncthreads();  // only barrier per iteration
        float4 w4 = red4[iter & 1][lane & 15];
        #pragma unroll
        for (int off = 1; off < 16; off <<= 1) {
            w4.x += __shfl_xor(w4.x, off);
            w4.y += __shfl_xor(w4.y, off);
            w4.z += __shfl_xor(w4.z, off);
        }
        float inv = __builtin_amdgcn_rcpf(w4.x);
        X0 = w4.y * inv;  // uniform across block
        X1 = w4.z * inv;
    }

    // hy[h] = enc_s_w[h,0]*X0 + enc_s_w[h,1]*X1 + enc_s_b[h]
    if (t < HH)
        hy_sh[t] = fmaf(enc_s_w[2 * t], X0, fmaf(enc_s_w[2 * t + 1], X1, enc_s_b[t]));
    __syncthreads();

    // out[b] = lin_w @ relu(dense_w @ hy + dense_b) + lin_b
    float o = 0.f;
    if (t < HH) {
        const float4* dw4 = (const float4*)(dense_w + t * HH);
        const float4* hy4 = (const float4*)hy_sh;
        float r = dense_b[t];
        #pragma unroll 4
        for (int k = 0; k < HH / 4; ++k) {
            float4 d4 = dw4[k], h4v = hy4[k];
            r = fmaf(d4.x, h4v.x, fmaf(d4.y, h4v.y, fmaf(d4.z, h4v.z, fmaf(d4.w, h4v.w, r))));
        }
        o = lin_w[t] * fmaxf(r, 0.f);
    }
    #pragma unroll
    for (int off = 32; off > 0; off >>= 1) o += __shfl_xor(o, off);
    if (lane == 0) red4[0][wave].x = o;
    __syncthreads();
    if (t == 0) {
        float s = 0.f;
        for (int i = 0; i < NW; ++i) s += red4[0][i].x;
        out[b] = s + lin_b[0];
    }
}

extern "C" void kernel_launch(void* const* d_in, const int* in_sizes, int n_in,
                              void* d_out, int out_size, void* d_ws, size_t ws_size,
                              hipStream_t stream) {
    const float* stat    = (const float*)d_in[0];
    const float* dyn     = (const float*)d_in[1];
    const float* enc_s_w = (const float*)d_in[2];
    const float* enc_s_b = (const float*)d_in[3];
    const float* enc_d_w = (const float*)d_in[4];
    const float* enc_d_b = (const float*)d_in[5];
    const float* v       = (const float*)d_in[6];
    const float* W       = (const float*)d_in[7];
    const float* dense_w = (const float*)d_in[8];
    const float* dense_b = (const float*)d_in[9];
    const float* lin_w   = (const float*)d_in[10];
    const float* lin_b   = (const float*)d_in[11];
    float* out = (float*)d_out;
    float* ws  = (float*)d_ws;

    const int B = in_sizes[0] / (2 * SS);

    hipLaunchKernelGGL(sc_fold, dim3(4), dim3(NT), 0, stream,
                       enc_s_w, enc_s_b, enc_d_w, enc_d_b, v, W, ws);
    hipLaunchKernelGGL(sc_main, dim3(B), dim3(NT), 0, stream,
                       stat, dyn, ws, enc_s_w, enc_s_b, dense_w, dense_b,
                       lin_w, lin_b, out);
}